// Round 1
// baseline (84.743 us; speedup 1.0000x reference)
//
#include <hip/hip_runtime.h>
#include <cmath>

// Problem constants
#define BATCH 64
#define SEQLEN 512
#define NFEAT 64
#define NPATCH 125
#define PATCHLEN 16
#define STRIDE_ 4
#define PREDLEN 96
#define NCOLS 500   // NPATCH * 4 qubits

// One block per (b, m) row. 128 threads:
//  - threads 0..7  : build the 8 Rot gate matrices into LDS
//  - threads 0..124: simulate one patch each (4-qubit statevector in regs)
//  - threads 0..95 : head GEMM dot-product for one output element
__global__ __launch_bounds__(128) void qml_fused_kernel(
    const float* __restrict__ x,     // [B, L, M]
    const float* __restrict__ w,     // [2, 4, 3]
    const float* __restrict__ hw,    // [PRED, NCOLS]
    const float* __restrict__ hb,    // [PRED]
    float* __restrict__ out)         // [B, PRED, M]
{
    __shared__ float gates[8][8];            // U00r,U00i,U01r,U01i,U10r,U10i,U11r,U11i
    __shared__ __align__(16) float enc[NCOLS];

    const int tid = threadIdx.x;
    const int bm  = blockIdx.x;
    const int m   = bm & 63;
    const int b   = bm >> 6;

    // --- build gate matrices (same for all blocks; 24-float weight array) ---
    if (tid < 8) {
        const float phi   = w[tid * 3 + 0];
        const float theta = w[tid * 3 + 1];
        const float omega = w[tid * 3 + 2];
        const float c  = cosf(0.5f * theta), s  = sinf(0.5f * theta);
        const float hf = 0.5f * (phi + omega), df = 0.5f * (phi - omega);
        const float ch = cosf(hf), sh = sinf(hf);
        const float cd = cosf(df), sd = sinf(df);
        gates[tid][0] =  ch * c;  gates[tid][1] = -sh * c;   // U00 = e^{-i hf} c
        gates[tid][2] = -cd * s;  gates[tid][3] = -sd * s;   // U01 = -e^{+i df} s
        gates[tid][4] =  cd * s;  gates[tid][5] = -sd * s;   // U10 = e^{-i df} s
        gates[tid][6] =  ch * c;  gates[tid][7] =  sh * c;   // U11 = e^{+i hf} c
    }
    __syncthreads();

    // --- phase 1: per-patch quantum encoder ---
    if (tid < NPATCH) {
        const int p = tid;
        float re[16], im[16];
        float ss = 0.f;
        const float* xp = x + ((size_t)b * SEQLEN + (size_t)p * STRIDE_) * NFEAT + m;
        #pragma unroll
        for (int j = 0; j < PATCHLEN; ++j) {
            const float v = xp[j * NFEAT] + 1e-6f;
            re[j] = v;
            im[j] = 0.f;
            ss += v * v;
        }
        const float inv = rsqrtf(ss);
        #pragma unroll
        for (int j = 0; j < PATCHLEN; ++j) re[j] *= inv;

        #pragma unroll
        for (int l = 0; l < 2; ++l) {
            // Rot on each wire q (wire q <-> bit (8 >> q), wire0 = MSB)
            #pragma unroll
            for (int q = 0; q < 4; ++q) {
                const int g = l * 4 + q;
                const float u00r = gates[g][0], u00i = gates[g][1];
                const float u01r = gates[g][2], u01i = gates[g][3];
                const float u10r = gates[g][4], u10i = gates[g][5];
                const float u11r = gates[g][6], u11i = gates[g][7];
                const int bit = 8 >> q;
                #pragma unroll
                for (int k = 0; k < 16; ++k) {
                    if (k & bit) continue;
                    const int k1 = k | bit;
                    const float a0r = re[k],  a0i = im[k];
                    const float a1r = re[k1], a1i = im[k1];
                    re[k]  = u00r * a0r - u00i * a0i + u01r * a1r - u01i * a1i;
                    im[k]  = u00r * a0i + u00i * a0r + u01r * a1i + u01i * a1r;
                    re[k1] = u10r * a0r - u10i * a0i + u11r * a1r - u11i * a1i;
                    im[k1] = u10r * a0i + u10i * a0r + u11r * a1i + u11i * a1r;
                }
            }
            // CNOT ring, range r = (l % 3) + 1
            const int r = (l % 3) + 1;
            #pragma unroll
            for (int i = 0; i < 4; ++i) {
                const int cb = 8 >> i;
                const int tb = 8 >> ((i + r) & 3);
                #pragma unroll
                for (int k = 0; k < 16; ++k) {
                    if ((k & cb) && !(k & tb)) {
                        const int k1 = k | tb;
                        float t;
                        t = re[k]; re[k] = re[k1]; re[k1] = t;
                        t = im[k]; im[k] = im[k1]; im[k1] = t;
                    }
                }
            }
        }

        // <Z_q> from probabilities
        #pragma unroll
        for (int q = 0; q < 4; ++q) {
            const int bit = 8 >> q;
            float z = 0.f;
            #pragma unroll
            for (int k = 0; k < 16; ++k) {
                const float pk = re[k] * re[k] + im[k] * im[k];
                z += (k & bit) ? -pk : pk;
            }
            enc[p * 4 + q] = z;
        }
    }
    __syncthreads();

    // --- phase 2: head GEMM row: out[b, o, m] = enc . hw[o, :] + hb[o] ---
    if (tid < PREDLEN) {
        const int o = tid;
        float acc = hb[o];
        const float4* hw4  = reinterpret_cast<const float4*>(hw + (size_t)o * NCOLS);
        const float4* enc4 = reinterpret_cast<const float4*>(enc);
        #pragma unroll 5
        for (int k = 0; k < NCOLS / 4; ++k) {
            const float4 hv = hw4[k];
            const float4 ev = enc4[k];
            acc += ev.x * hv.x + ev.y * hv.y + ev.z * hv.z + ev.w * hv.w;
        }
        out[((size_t)b * PREDLEN + o) * NFEAT + m] = acc;
    }
}

extern "C" void kernel_launch(void* const* d_in, const int* in_sizes, int n_in,
                              void* d_out, int out_size, void* d_ws, size_t ws_size,
                              hipStream_t stream) {
    const float* x  = (const float*)d_in[0];   // [64, 512, 64]
    const float* w  = (const float*)d_in[1];   // [2, 4, 3]
    const float* hw = (const float*)d_in[2];   // [96, 500]
    const float* hb = (const float*)d_in[3];   // [96]
    float* out = (float*)d_out;                // [64, 96, 64]

    dim3 grid(BATCH * NFEAT);  // 4096 blocks, one per (b, m)
    dim3 block(128);
    qml_fused_kernel<<<grid, block, 0, stream>>>(x, w, hw, hb, out);
}

// Round 2
// 54.689 us; speedup vs baseline: 1.5496x; 1.5496x over previous
//
#include <hip/hip_runtime.h>
#include <cmath>

// Problem constants
#define BATCH 64
#define SEQLEN 512
#define NFEAT 64
#define NPATCH 125
#define PATCHLEN 16
#define STRIDE_ 4
#define PREDLEN 96
#define NCOLS 500    // NPATCH * 4 qubits
#define MG 8         // m's per block
#define NMG (NFEAT / MG)
#define TPAD 521     // xt row pad (odd -> <=2-way bank aliasing on sim reads)
#define EPAD 508     // enc row pad (16B-aligned, bank-spread across m lanes)

// One block per (b, m-group of 8). 256 threads.
//  phase 0: threads 0..7 build Rot gate matrices; all threads stage
//           x[b, :, m0:m0+8] coalesced (float4) into LDS transposed xt[m][t]
//  phase 1: 1000 sims (8 m x 125 patches), ~4 per thread, state in regs
//  phase 2: head GEMM out[b, 0:96, m0:m0+8]; thread (m, o0) does 3 rows
__global__ __launch_bounds__(256) void qml_fused_kernel(
    const float* __restrict__ x,     // [B, L, M]
    const float* __restrict__ w,     // [2, 4, 3]
    const float* __restrict__ hw,    // [PRED, NCOLS]
    const float* __restrict__ hb,    // [PRED]
    float* __restrict__ out)         // [B, PRED, M]
{
    __shared__ float gates[8][8];                    // U00r,U00i,U01r,U01i,U10r,U10i,U11r,U11i
    __shared__ float xt[MG][TPAD];                   // 16.7 KB
    __shared__ __align__(16) float enc[MG][EPAD];    // 16.3 KB

    const int tid = threadIdx.x;
    const int blk = blockIdx.x;
    const int b   = blk >> 3;        // / NMG
    const int mg  = blk & (NMG - 1);
    const int m0  = mg * MG;

    // --- gate matrices ---
    if (tid < 8) {
        const float phi   = w[tid * 3 + 0];
        const float theta = w[tid * 3 + 1];
        const float omega = w[tid * 3 + 2];
        const float c  = cosf(0.5f * theta), s  = sinf(0.5f * theta);
        const float hf = 0.5f * (phi + omega), df = 0.5f * (phi - omega);
        const float ch = cosf(hf), sh = sinf(hf);
        const float cd = cosf(df), sd = sinf(df);
        gates[tid][0] =  ch * c;  gates[tid][1] = -sh * c;   // U00 = e^{-i hf} c
        gates[tid][2] = -cd * s;  gates[tid][3] = -sd * s;   // U01 = -e^{+i df} s
        gates[tid][4] =  cd * s;  gates[tid][5] = -sd * s;   // U10 = e^{-i df} s
        gates[tid][6] =  ch * c;  gates[tid][7] =  sh * c;   // U11 = e^{+i hf} c
    }

    // --- coalesced staging: x[b, t, m0+4h+c] -> xt[4h+c][t] ---
    {
        const float* xb = x + (size_t)b * SEQLEN * NFEAT + m0;
        #pragma unroll
        for (int r = 0; r < 4; ++r) {
            const int idx  = tid + r * 256;          // 0..1023
            const int t    = idx >> 1;
            const int half = idx & 1;
            const float4 v = *reinterpret_cast<const float4*>(xb + (size_t)t * NFEAT + 4 * half);
            xt[4 * half + 0][t] = v.x;
            xt[4 * half + 1][t] = v.y;
            xt[4 * half + 2][t] = v.z;
            xt[4 * half + 3][t] = v.w;
        }
    }
    __syncthreads();

    // --- phase 1: quantum encoder sims ---
    for (int s = tid; s < MG * NPATCH; s += 256) {
        const int m = s & (MG - 1);
        const int p = s >> 3;

        float re[16], im[16];
        float ss = 0.f;
        #pragma unroll
        for (int j = 0; j < PATCHLEN; ++j) {
            const float v = xt[m][p * STRIDE_ + j] + 1e-6f;
            re[j] = v;
            im[j] = 0.f;
            ss += v * v;
        }
        const float inv = rsqrtf(ss);
        #pragma unroll
        for (int j = 0; j < PATCHLEN; ++j) re[j] *= inv;

        #pragma unroll
        for (int l = 0; l < 2; ++l) {
            #pragma unroll
            for (int q = 0; q < 4; ++q) {
                const int g = l * 4 + q;
                const float u00r = gates[g][0], u00i = gates[g][1];
                const float u01r = gates[g][2], u01i = gates[g][3];
                const float u10r = gates[g][4], u10i = gates[g][5];
                const float u11r = gates[g][6], u11i = gates[g][7];
                const int bit = 8 >> q;
                #pragma unroll
                for (int k = 0; k < 16; ++k) {
                    if (k & bit) continue;
                    const int k1 = k | bit;
                    const float a0r = re[k],  a0i = im[k];
                    const float a1r = re[k1], a1i = im[k1];
                    re[k]  = u00r * a0r - u00i * a0i + u01r * a1r - u01i * a1i;
                    im[k]  = u00r * a0i + u00i * a0r + u01r * a1i + u01i * a1r;
                    re[k1] = u10r * a0r - u10i * a0i + u11r * a1r - u11i * a1i;
                    im[k1] = u10r * a0i + u10i * a0r + u11r * a1i + u11i * a1r;
                }
            }
            const int r = (l % 3) + 1;
            #pragma unroll
            for (int i = 0; i < 4; ++i) {
                const int cb = 8 >> i;
                const int tb = 8 >> ((i + r) & 3);
                #pragma unroll
                for (int k = 0; k < 16; ++k) {
                    if ((k & cb) && !(k & tb)) {
                        const int k1 = k | tb;
                        float t;
                        t = re[k]; re[k] = re[k1]; re[k1] = t;
                        t = im[k]; im[k] = im[k1]; im[k1] = t;
                    }
                }
            }
        }

        float z[4];
        #pragma unroll
        for (int q = 0; q < 4; ++q) {
            const int bit = 8 >> q;
            float zz = 0.f;
            #pragma unroll
            for (int k = 0; k < 16; ++k) {
                const float pk = re[k] * re[k] + im[k] * im[k];
                zz += (k & bit) ? -pk : pk;
            }
            z[q] = zz;
        }
        *reinterpret_cast<float4*>(&enc[m][4 * p]) = make_float4(z[0], z[1], z[2], z[3]);
    }
    __syncthreads();

    // --- phase 2: head GEMM: out[b, o, m0+m] = enc[m] . hw[o] + hb[o] ---
    {
        const int m  = tid & (MG - 1);
        const int o0 = tid >> 3;                 // 0..31
        float acc0 = hb[o0];
        float acc1 = hb[o0 + 32];
        float acc2 = hb[o0 + 64];
        const float4* e4 = reinterpret_cast<const float4*>(&enc[m][0]);
        const float4* h0 = reinterpret_cast<const float4*>(hw + (size_t)(o0     ) * NCOLS);
        const float4* h1 = reinterpret_cast<const float4*>(hw + (size_t)(o0 + 32) * NCOLS);
        const float4* h2 = reinterpret_cast<const float4*>(hw + (size_t)(o0 + 64) * NCOLS);
        #pragma unroll 5
        for (int k = 0; k < NCOLS / 4; ++k) {
            const float4 ev = e4[k];
            const float4 a  = h0[k];
            const float4 bb = h1[k];
            const float4 cc = h2[k];
            acc0 += ev.x * a.x  + ev.y * a.y  + ev.z * a.z  + ev.w * a.w;
            acc1 += ev.x * bb.x + ev.y * bb.y + ev.z * bb.z + ev.w * bb.w;
            acc2 += ev.x * cc.x + ev.y * cc.y + ev.z * cc.z + ev.w * cc.w;
        }
        float* ob = out + ((size_t)b * PREDLEN) * NFEAT + m0 + m;
        ob[(size_t)(o0     ) * NFEAT] = acc0;
        ob[(size_t)(o0 + 32) * NFEAT] = acc1;
        ob[(size_t)(o0 + 64) * NFEAT] = acc2;
    }
}

extern "C" void kernel_launch(void* const* d_in, const int* in_sizes, int n_in,
                              void* d_out, int out_size, void* d_ws, size_t ws_size,
                              hipStream_t stream) {
    const float* x  = (const float*)d_in[0];   // [64, 512, 64]
    const float* w  = (const float*)d_in[1];   // [2, 4, 3]
    const float* hw = (const float*)d_in[2];   // [96, 500]
    const float* hb = (const float*)d_in[3];   // [96]
    float* out = (float*)d_out;                // [64, 96, 64]

    dim3 grid(BATCH * NMG);   // 512 blocks: (b, m-group)
    dim3 block(256);
    qml_fused_kernel<<<grid, block, 0, stream>>>(x, w, hw, hb, out);
}